// Round 3
// baseline (378.412 us; speedup 1.0000x reference)
//
#include <hip/hip_runtime.h>
#include <math.h>

#define EE 5120
#define DD 2560
#define BB 32

// ---------------------------------------------------------------------------
// K0: transpose x (B,D) -> xT (D,B); zero dbc accumulator.
__global__ __launch_bounds__(256) void k0_prep(const float* __restrict__ x,
                                               float* __restrict__ xT,
                                               float* __restrict__ dbc) {
  int g = blockIdx.x * 256 + threadIdx.x;
  if (g < BB * DD) {
    int b = g / DD, k = g % DD;
    xT[k * BB + b] = x[g];
  }
  if (g < BB * 192) dbc[g] = 0.f;
}

// ---------------------------------------------------------------------------
// Unified skinny GEMM: C[b][col] = sum_k xsrc[k][b] * W[k][col]
// Block: 128 columns (lane owns 2 via float2 loads), k-range 320 staged in LDS
// (40 KB), 4 waves = 4 inner k-slices of 80. Per k per lane: 1 float2 weight
// load + 8 broadcast ds_read_b128 of x + 64 FMAs. Rotating 4-deep weight
// prefetch. Cross-wave reduce in LDS (aliased over x-stage), float2 stores to
// partials P[(so*32+b)*pstride + col].
__device__ __forceinline__ void compute4(float2* __restrict__ acc,
                                         const float2* __restrict__ wcur,
                                         const float* __restrict__ xw, int kk) {
#pragma unroll
  for (int j = 0; j < 4; ++j) {
    const float4* __restrict__ xk = (const float4*)(xw + (kk + j) * BB);
    float2 wj = wcur[j];
#pragma unroll
    for (int q = 0; q < 8; ++q) {
      float4 xv = xk[q];
      acc[q * 4 + 0].x = fmaf(xv.x, wj.x, acc[q * 4 + 0].x);
      acc[q * 4 + 0].y = fmaf(xv.x, wj.y, acc[q * 4 + 0].y);
      acc[q * 4 + 1].x = fmaf(xv.y, wj.x, acc[q * 4 + 1].x);
      acc[q * 4 + 1].y = fmaf(xv.y, wj.y, acc[q * 4 + 1].y);
      acc[q * 4 + 2].x = fmaf(xv.z, wj.x, acc[q * 4 + 2].x);
      acc[q * 4 + 2].y = fmaf(xv.z, wj.y, acc[q * 4 + 2].y);
      acc[q * 4 + 3].x = fmaf(xv.w, wj.x, acc[q * 4 + 3].x);
      acc[q * 4 + 3].y = fmaf(xv.w, wj.y, acc[q * 4 + 3].y);
    }
  }
}

__global__ __launch_bounds__(256, 4) void gemm_sk(const float* __restrict__ W0,
                                                  const float* __restrict__ W1,
                                                  int wsplit, int wstride,
                                                  const float* __restrict__ xsrc,
                                                  float* __restrict__ P,
                                                  int pstride, int ncb) {
  __shared__ float smem[10240];             // 40 KB: x-stage, aliased by reduce
  const int cb   = blockIdx.x % ncb;
  const int so   = blockIdx.x / ncb;
  const int lane = threadIdx.x & 63;
  const int wv   = threadIdx.x >> 6;        // inner k-slice 0..3
  const int ccol = cb * 128 + lane * 2;
  const float* __restrict__ W = (ccol < wsplit) ? W0 : W1;
  const int wc = (ccol < wsplit) ? ccol : ccol - wsplit;
  const int k0 = so * 320;

  // stage x slice (320 k x 32 b = 10240 contiguous floats) coalesced
  {
    const float4* __restrict__ src = (const float4*)(xsrc + (size_t)k0 * BB);
    float4* __restrict__ dst = (float4*)smem;
    for (int i = threadIdx.x; i < 2560; i += 256) dst[i] = src[i];
  }
  __syncthreads();

  float2 acc[32];
#pragma unroll
  for (int b = 0; b < 32; ++b) acc[b] = make_float2(0.f, 0.f);

  const int kw = wv * 80;
  const float* __restrict__ wp = W + (size_t)(k0 + kw) * wstride + wc;
  const float* __restrict__ xw = smem + kw * BB;

  float2 wb[4];
#pragma unroll
  for (int p = 0; p < 4; ++p) wb[p] = *(const float2*)(wp + (size_t)p * wstride);

  for (int kk = 0; kk < 76; kk += 4) {
    float2 wcur[4];
#pragma unroll
    for (int p = 0; p < 4; ++p) wcur[p] = wb[p];
#pragma unroll
    for (int p = 0; p < 4; ++p)
      wb[p] = *(const float2*)(wp + (size_t)(kk + 4 + p) * wstride);
    compute4(acc, wcur, xw, kk);
  }
  compute4(acc, wb, xw, 76);               // epilogue: rows 76..79

  // cross-wave reduce: 8 phases, red(w,lane,i)=smem[(w*64+lane)*9+i] (9 coprime 32)
#pragma unroll 1
  for (int p = 0; p < 8; ++p) {
    __syncthreads();
#pragma unroll
    for (int q = 0; q < 4; ++q) {
      smem[(wv * 64 + lane) * 9 + q * 2 + 0] = acc[p * 4 + q].x;
      smem[(wv * 64 + lane) * 9 + q * 2 + 1] = acc[p * 4 + q].y;
    }
    __syncthreads();
    float sx = smem[(0 * 64 + lane) * 9 + wv * 2] + smem[(1 * 64 + lane) * 9 + wv * 2] +
               smem[(2 * 64 + lane) * 9 + wv * 2] + smem[(3 * 64 + lane) * 9 + wv * 2];
    float sy = smem[(0 * 64 + lane) * 9 + wv * 2 + 1] + smem[(1 * 64 + lane) * 9 + wv * 2 + 1] +
               smem[(2 * 64 + lane) * 9 + wv * 2 + 1] + smem[(3 * 64 + lane) * 9 + wv * 2 + 1];
    int b = p * 4 + wv;
    *(float2*)&P[((size_t)(so * BB + b)) * pstride + ccol] = make_float2(sx, sy);
  }
}

// ---------------------------------------------------------------------------
// K1b: reduce the 8 outer partials, fuse conv(4-tap)+silu -> xt, silu -> res.
__global__ __launch_bounds__(256) void k1b_epilogue(const float* __restrict__ P1,
                                                    const float* __restrict__ cs,
                                                    const float* __restrict__ cw,
                                                    const float* __restrict__ cbv,
                                                    float* __restrict__ xt,
                                                    float* __restrict__ res) {
  int g = blockIdx.x * 256 + threadIdx.x;     // 0..163839
  int e = g % EE;
  int b = g / EE;
  float xs = 0.f, xm = 0.f;
#pragma unroll
  for (int so = 0; so < 8; ++so) {
    xs += P1[((size_t)(so * BB + b)) * 10240 + e];
    xm += P1[((size_t)(so * BB + b)) * 10240 + EE + e];
  }
  size_t be = (size_t)b * EE + e;
  const size_t T = (size_t)BB * EE;
  float conv = cs[be] * cw[be] + cs[T + be] * cw[T + be] +
               cs[2 * T + be] * cw[2 * T + be] + xs * cw[3 * T + be] + cbv[be];
  float sig = 1.f / (1.f + expf(-conv));
  xt[be] = conv * sig;
  float sm = 1.f / (1.f + expf(-xm));
  res[be] = xm * sm;
}

// ---------------------------------------------------------------------------
// K2: dbc = xt @ Wx  (32 x 5120 x 192). 192 blocks = 3 cb x 64 k-splits.
__global__ __launch_bounds__(256) void k2_dbc(const float* __restrict__ xt,
                                              const float* __restrict__ Wx,
                                              float* __restrict__ dbc) {
  const int bid  = blockIdx.x;
  const int cbi  = bid % 3;
  const int so   = bid / 3;                   // 0..63
  const int lane = threadIdx.x & 63;
  const int j    = cbi * 64 + lane;           // 0..191
  const int k0   = so * 80 + (int)(threadIdx.x >> 6) * 20;

  float acc[BB];
#pragma unroll
  for (int b = 0; b < BB; ++b) acc[b] = 0.f;

  for (int kk = 0; kk < 20; kk += 4) {
    int k = k0 + kk;
    float w0 = Wx[(size_t)(k + 0) * 192 + j];
    float w1 = Wx[(size_t)(k + 1) * 192 + j];
    float w2 = Wx[(size_t)(k + 2) * 192 + j];
    float w3 = Wx[(size_t)(k + 3) * 192 + j];
#pragma unroll
    for (int b = 0; b < BB; ++b) acc[b] = fmaf(xt[(size_t)b * EE + k + 0], w0, acc[b]);
#pragma unroll
    for (int b = 0; b < BB; ++b) acc[b] = fmaf(xt[(size_t)b * EE + k + 1], w1, acc[b]);
#pragma unroll
    for (int b = 0; b < BB; ++b) acc[b] = fmaf(xt[(size_t)b * EE + k + 2], w2, acc[b]);
#pragma unroll
    for (int b = 0; b < BB; ++b) acc[b] = fmaf(xt[(size_t)b * EE + k + 3], w3, acc[b]);
  }

  __shared__ float red[4][64][17];
  const int ksid = threadIdx.x >> 6;
#pragma unroll
  for (int half = 0; half < 2; ++half) {
    __syncthreads();
#pragma unroll
    for (int i = 0; i < 16; ++i) red[ksid][lane][i] = acc[half * 16 + i];
    __syncthreads();
#pragma unroll
    for (int jj = 0; jj < 4; ++jj) {
      int bi = ksid * 4 + jj;
      float v = red[0][lane][bi] + red[1][lane][bi] +
                red[2][lane][bi] + red[3][lane][bi];
      int b = half * 16 + bi;
      atomicAdd(&dbc[b * 192 + j], v);
    }
  }
}

// ---------------------------------------------------------------------------
// K3: dt-GEMM (K=160) + softplus + SSM step + D*xt + residual mul -> zT (E,B).
__global__ __launch_bounds__(256) void k3_ssm(const float* __restrict__ dbc,
                                              const float* __restrict__ Wdt,
                                              const float* __restrict__ dt_bias,
                                              const float* __restrict__ A_log,
                                              const float* __restrict__ Dvec,
                                              const float* __restrict__ h,
                                              const float* __restrict__ xt,
                                              const float* __restrict__ res,
                                              float* __restrict__ zT) {
  const int eb   = blockIdx.x % 80;
  const int bg   = blockIdx.x / 80;           // 0..3
  const int lane = threadIdx.x & 63;
  const int sub  = __builtin_amdgcn_readfirstlane((int)(threadIdx.x >> 6));
  const int e    = eb * 64 + lane;
  const int bq   = bg * 4 + sub;              // 0..15
  const int b0   = bq * 2, b1 = b0 + 1;

  float a0 = 0.f, a1 = 0.f;
  const float* __restrict__ d0 = dbc + b0 * 192;
  const float* __restrict__ d1 = dbc + b1 * 192;
  for (int r = 0; r < 160; r += 4) {
    float w0 = Wdt[(size_t)(r + 0) * EE + e];
    float w1 = Wdt[(size_t)(r + 1) * EE + e];
    float w2 = Wdt[(size_t)(r + 2) * EE + e];
    float w3 = Wdt[(size_t)(r + 3) * EE + e];
    a0 = fmaf(d0[r + 0], w0, a0);  a1 = fmaf(d1[r + 0], w0, a1);
    a0 = fmaf(d0[r + 1], w1, a0);  a1 = fmaf(d1[r + 1], w1, a1);
    a0 = fmaf(d0[r + 2], w2, a0);  a1 = fmaf(d1[r + 2], w2, a1);
    a0 = fmaf(d0[r + 3], w3, a0);  a1 = fmaf(d1[r + 3], w3, a1);
  }

  float An[16];
#pragma unroll
  for (int n = 0; n < 16; ++n) An[n] = -expf(A_log[e * 16 + n]);
  const float bias = dt_bias[e];
  const float Dv = Dvec[e];

#pragma unroll
  for (int t = 0; t < 2; ++t) {
    int b = t ? b1 : b0;
    float a = t ? a1 : a0;
    float v = a + bias;
    float dt = (v > 20.f) ? v : log1pf(expf(v));
    size_t be = (size_t)b * EE + e;
    float xb = xt[be];
    const float* __restrict__ hb = h + be * 16;
    const float* __restrict__ Bm = dbc + b * 192 + 160;
    const float* __restrict__ Cm = dbc + b * 192 + 176;
    float y = 0.f;
#pragma unroll
    for (int n = 0; n < 16; ++n) {
      float dA = expf(dt * An[n]);
      float hn = fmaf(hb[n], dA, dt * Bm[n] * xb);
      y = fmaf(hn, Cm[n], y);
    }
    y = fmaf(Dv, xb, y);
    zT[e * BB + b] = y * res[be];
  }
}

// K4b: reduce 16 partials -> final output (B, D) flat.
__global__ __launch_bounds__(256) void k4b_reduce(const float* __restrict__ P4,
                                                  float* __restrict__ out) {
  int g = blockIdx.x * 256 + threadIdx.x;     // 0..81919 == b*DD + d
  int d = g % DD;
  int b = g / DD;
  float s = 0.f;
#pragma unroll
  for (int so = 0; so < 16; ++so) s += P4[((size_t)(so * BB + b)) * DD + d];
  out[g] = s;
}

// ---------------------------------------------------------------------------
extern "C" void kernel_launch(void* const* d_in, const int* in_sizes, int n_in,
                              void* d_out, int out_size, void* d_ws, size_t ws_size,
                              hipStream_t stream) {
  const float* x       = (const float*)d_in[0];
  const float* Wssm    = (const float*)d_in[1];
  const float* Wmlp    = (const float*)d_in[2];
  const float* Wout    = (const float*)d_in[3];
  const float* conv_w  = (const float*)d_in[4];
  const float* conv_b  = (const float*)d_in[5];
  const float* conv_st = (const float*)d_in[6];
  const float* Wx      = (const float*)d_in[7];
  const float* Wdt     = (const float*)d_in[8];
  const float* dt_bias = (const float*)d_in[9];
  const float* A_log   = (const float*)d_in[10];
  const float* Dvec    = (const float*)d_in[11];
  const float* h       = (const float*)d_in[12];
  float* out = (float*)d_out;

  float* ws = (float*)d_ws;
  float* xT  = ws;                       // 81,920
  float* P1  = xT  + 81920;              // 2,621,440  (8 splits x 32 x 10240)
  float* xt  = P1  + 2621440;            // 163,840
  float* res = xt  + 163840;             // 163,840
  float* dbc = res + 163840;             // 6,144
  float* zT  = dbc + 6144;               // 163,840
  float* P4  = zT  + 163840;             // 1,310,720  (16 splits x 32 x 2560)

  hipLaunchKernelGGL(k0_prep,     dim3(320),  dim3(256), 0, stream, x, xT, dbc);
  hipLaunchKernelGGL(gemm_sk,     dim3(640),  dim3(256), 0, stream,
                     Wssm, Wmlp, EE, EE, xT, P1, 10240, 80);
  hipLaunchKernelGGL(k1b_epilogue,dim3(640),  dim3(256), 0, stream, P1, conv_st, conv_w, conv_b, xt, res);
  hipLaunchKernelGGL(k2_dbc,      dim3(192),  dim3(256), 0, stream, xt, Wx, dbc);
  hipLaunchKernelGGL(k3_ssm,      dim3(320),  dim3(256), 0, stream, dbc, Wdt, dt_bias, A_log, Dvec, h, xt, res, zT);
  hipLaunchKernelGGL(gemm_sk,     dim3(320),  dim3(256), 0, stream,
                     Wout, Wout, 1 << 30, DD, zT, P4, DD, 20);
  hipLaunchKernelGGL(k4b_reduce,  dim3(320),  dim3(256), 0, stream, P4, out);
}

// Round 4
// 271.644 us; speedup vs baseline: 1.3930x; 1.3930x over previous
//
#include <hip/hip_runtime.h>
#include <math.h>

#define EE 5120
#define DD 2560
#define BB 32

// Async global->LDS DMA, 16B per lane: lane i's 16B from g(lane) lands at
// wave-uniform base l + i*16. Compiler cannot re-serialize these; vmcnt-tracked.
__device__ __forceinline__ void g2l16(const float* g, float* l) {
  __builtin_amdgcn_global_load_lds(
      (const __attribute__((address_space(1))) void*)g,
      (__attribute__((address_space(3))) void*)l, 16, 0, 0);
}

// ---------------------------------------------------------------------------
// K0: transpose x (B,D) -> xT (D,B); zero dbc accumulator.
__global__ __launch_bounds__(256) void k0_prep(const float* __restrict__ x,
                                               float* __restrict__ xT,
                                               float* __restrict__ dbc) {
  int g = blockIdx.x * 256 + threadIdx.x;
  if (g < BB * DD) {
    int b = g / DD, k = g % DD;
    xT[k * BB + b] = x[g];
  }
  if (g < BB * 192) dbc[g] = 0.f;
}

// ---------------------------------------------------------------------------
// Unified skinny GEMM: P[(so*32+b)*pstride + col] = sum_k xsrc[k][b]*W[k][col]
// Block = 4 waves, 64 cols; wave wv owns k-slice [so*320+wv*80, +80), staged
// through its private 40x64 LDS buffer in 2 async-DMA chunks (10x1KB instrs
// in flight per chunk). Weights: ds_read_b32 (2-way bank alias = free).
// x: wave-uniform scalar loads. acc[32] = R1's proven no-spill shape.
__global__ __launch_bounds__(256) void gemm_sk(const float* __restrict__ W0,
                                               const float* __restrict__ W1,
                                               int wsplit, int wstride,
                                               const float* __restrict__ xsrc,
                                               float* __restrict__ P,
                                               int pstride, int ncb) {
  __shared__ float smem[10240];              // 40 KB: stage 4x(40x64); reduce aliases
  const int cb   = blockIdx.x % ncb;
  const int so   = blockIdx.x / ncb;
  const int lane = threadIdx.x & 63;
  const int wv   = __builtin_amdgcn_readfirstlane((int)(threadIdx.x >> 6));
  const int c0   = cb * 64;
  const float* __restrict__ W = (c0 < wsplit) ? W0 : W1;
  const int wc0  = (c0 < wsplit) ? c0 : c0 - wsplit;
  const int kw   = so * 320 + wv * 80;

  float acc[BB];
#pragma unroll
  for (int b = 0; b < BB; ++b) acc[b] = 0.f;

  float* stage = smem + wv * 2560;           // this wave's 40x64 buffer
  const int rg = lane >> 4;                  // row within 4-row group
  const int cg = (lane & 15) * 4;            // col offset in floats

  for (int ch = 0; ch < 2; ++ch) {
    const int kc = kw + ch * 40;
    __builtin_amdgcn_s_waitcnt(0);           // prior chunk's LDS reads retired
#pragma unroll
    for (int j = 0; j < 10; ++j) {
      const float* g = W + (size_t)(kc + j * 4 + rg) * wstride + wc0 + cg;
      g2l16(g, stage + (j * 4) * 64);
    }
    __builtin_amdgcn_s_waitcnt(0);           // DMA landed
    const float* __restrict__ xrow = xsrc + (size_t)kc * BB;
#pragma unroll 4
    for (int kk = 0; kk < 40; ++kk) {
      float w = stage[kk * 64 + lane];
#pragma unroll
      for (int b = 0; b < BB; ++b)
        acc[b] = fmaf(xrow[kk * BB + b], w, acc[b]);
    }
  }

  // cross-wave reduce, R1-proven pattern (stride 17, conflict-free)
#pragma unroll
  for (int half = 0; half < 2; ++half) {
    __syncthreads();
#pragma unroll
    for (int i = 0; i < 16; ++i)
      smem[(wv * 64 + lane) * 17 + i] = acc[half * 16 + i];
    __syncthreads();
#pragma unroll
    for (int j = 0; j < 4; ++j) {
      int bi = wv * 4 + j;
      float v = smem[(0 * 64 + lane) * 17 + bi] + smem[(1 * 64 + lane) * 17 + bi] +
                smem[(2 * 64 + lane) * 17 + bi] + smem[(3 * 64 + lane) * 17 + bi];
      int b = half * 16 + bi;
      P[((size_t)(so * BB + b)) * pstride + c0 + lane] = v;
    }
  }
}

// ---------------------------------------------------------------------------
// K1b: reduce the 8 outer partials, fuse conv(4-tap)+silu -> xt, silu -> res.
__global__ __launch_bounds__(256) void k1b_epilogue(const float* __restrict__ P1,
                                                    const float* __restrict__ cs,
                                                    const float* __restrict__ cw,
                                                    const float* __restrict__ cbv,
                                                    float* __restrict__ xt,
                                                    float* __restrict__ res) {
  int g = blockIdx.x * 256 + threadIdx.x;     // 0..163839
  int e = g % EE;
  int b = g / EE;
  float xs = 0.f, xm = 0.f;
#pragma unroll
  for (int so = 0; so < 8; ++so) {
    xs += P1[((size_t)(so * BB + b)) * 10240 + e];
    xm += P1[((size_t)(so * BB + b)) * 10240 + EE + e];
  }
  size_t be = (size_t)b * EE + e;
  const size_t T = (size_t)BB * EE;
  float conv = cs[be] * cw[be] + cs[T + be] * cw[T + be] +
               cs[2 * T + be] * cw[2 * T + be] + xs * cw[3 * T + be] + cbv[be];
  float sig = 1.f / (1.f + expf(-conv));
  xt[be] = conv * sig;
  float sm = 1.f / (1.f + expf(-xm));
  res[be] = xm * sm;
}

// ---------------------------------------------------------------------------
// K2: dbc = xt @ Wx  (32 x 5120 x 192). 192 blocks = 3 cb x 64 k-splits.
__global__ __launch_bounds__(256) void k2_dbc(const float* __restrict__ xt,
                                              const float* __restrict__ Wx,
                                              float* __restrict__ dbc) {
  const int bid  = blockIdx.x;
  const int cbi  = bid % 3;
  const int so   = bid / 3;                   // 0..63
  const int lane = threadIdx.x & 63;
  const int j    = cbi * 64 + lane;           // 0..191
  const int k0   = so * 80 + (int)(threadIdx.x >> 6) * 20;

  float acc[BB];
#pragma unroll
  for (int b = 0; b < BB; ++b) acc[b] = 0.f;

  for (int kk = 0; kk < 20; kk += 4) {
    int k = k0 + kk;
    float w0 = Wx[(size_t)(k + 0) * 192 + j];
    float w1 = Wx[(size_t)(k + 1) * 192 + j];
    float w2 = Wx[(size_t)(k + 2) * 192 + j];
    float w3 = Wx[(size_t)(k + 3) * 192 + j];
#pragma unroll
    for (int b = 0; b < BB; ++b) acc[b] = fmaf(xt[(size_t)b * EE + k + 0], w0, acc[b]);
#pragma unroll
    for (int b = 0; b < BB; ++b) acc[b] = fmaf(xt[(size_t)b * EE + k + 1], w1, acc[b]);
#pragma unroll
    for (int b = 0; b < BB; ++b) acc[b] = fmaf(xt[(size_t)b * EE + k + 2], w2, acc[b]);
#pragma unroll
    for (int b = 0; b < BB; ++b) acc[b] = fmaf(xt[(size_t)b * EE + k + 3], w3, acc[b]);
  }

  __shared__ float red[4][64][17];
  const int ksid = threadIdx.x >> 6;
#pragma unroll
  for (int half = 0; half < 2; ++half) {
    __syncthreads();
#pragma unroll
    for (int i = 0; i < 16; ++i) red[ksid][lane][i] = acc[half * 16 + i];
    __syncthreads();
#pragma unroll
    for (int jj = 0; jj < 4; ++jj) {
      int bi = ksid * 4 + jj;
      float v = red[0][lane][bi] + red[1][lane][bi] +
                red[2][lane][bi] + red[3][lane][bi];
      int b = half * 16 + bi;
      atomicAdd(&dbc[b * 192 + j], v);
    }
  }
}

// ---------------------------------------------------------------------------
// K3: dt-GEMM (K=160, Wdt tile async-staged to LDS) + softplus + SSM step
// + D*xt + residual mul -> zT (E,B). 320 blocks = 80 eb x 4 bg.
__global__ __launch_bounds__(256) void k3_ssm(const float* __restrict__ dbc,
                                              const float* __restrict__ Wdt,
                                              const float* __restrict__ dt_bias,
                                              const float* __restrict__ A_log,
                                              const float* __restrict__ Dvec,
                                              const float* __restrict__ h,
                                              const float* __restrict__ xt,
                                              const float* __restrict__ res,
                                              float* __restrict__ zT) {
  __shared__ float sw[10240];                 // 160 x 64 Wdt tile
  const int eb   = blockIdx.x % 80;
  const int bg   = blockIdx.x / 80;           // 0..3
  const int lane = threadIdx.x & 63;
  const int wv   = __builtin_amdgcn_readfirstlane((int)(threadIdx.x >> 6));
  const int e    = eb * 64 + lane;
  const int bq   = bg * 4 + wv;               // 0..15
  const int b0   = bq * 2, b1 = b0 + 1;

  {
    const int rg = lane >> 4, cg = (lane & 15) * 4;
#pragma unroll
    for (int j = 0; j < 10; ++j) {
      int r = wv * 40 + j * 4 + rg;
      g2l16(Wdt + (size_t)r * EE + eb * 64 + cg, sw + (wv * 40 + j * 4) * 64);
    }
  }
  __syncthreads();                            // barrier drains vmcnt -> DMA landed

  float a0 = 0.f, a1 = 0.f;
  const float* __restrict__ d0 = dbc + b0 * 192;
  const float* __restrict__ d1 = dbc + b1 * 192;
#pragma unroll 4
  for (int r = 0; r < 160; ++r) {
    float w = sw[r * 64 + lane];
    a0 = fmaf(d0[r], w, a0);
    a1 = fmaf(d1[r], w, a1);
  }

  float An[16];
#pragma unroll
  for (int n = 0; n < 16; ++n) An[n] = -expf(A_log[e * 16 + n]);
  const float bias = dt_bias[e];
  const float Dv = Dvec[e];

#pragma unroll
  for (int t = 0; t < 2; ++t) {
    int b = t ? b1 : b0;
    float a = t ? a1 : a0;
    float v = a + bias;
    float dt = (v > 20.f) ? v : log1pf(expf(v));
    size_t be = (size_t)b * EE + e;
    float xb = xt[be];
    const float* __restrict__ hb = h + be * 16;
    const float* __restrict__ Bm = dbc + b * 192 + 160;
    const float* __restrict__ Cm = dbc + b * 192 + 176;
    float y = 0.f;
#pragma unroll
    for (int n = 0; n < 16; ++n) {
      float dA = expf(dt * An[n]);
      float hn = fmaf(hb[n], dA, dt * Bm[n] * xb);
      y = fmaf(hn, Cm[n], y);
    }
    y = fmaf(Dv, xb, y);
    zT[e * BB + b] = y * res[be];
  }
}

// K4b: reduce 16 partials -> final output (B, D) flat.
__global__ __launch_bounds__(256) void k4b_reduce(const float* __restrict__ P4,
                                                  float* __restrict__ out) {
  int g = blockIdx.x * 256 + threadIdx.x;     // 0..81919 == b*DD + d
  int d = g % DD;
  int b = g / DD;
  float s = 0.f;
#pragma unroll
  for (int so = 0; so < 16; ++so) s += P4[((size_t)(so * BB + b)) * DD + d];
  out[g] = s;
}

// ---------------------------------------------------------------------------
extern "C" void kernel_launch(void* const* d_in, const int* in_sizes, int n_in,
                              void* d_out, int out_size, void* d_ws, size_t ws_size,
                              hipStream_t stream) {
  const float* x       = (const float*)d_in[0];
  const float* Wssm    = (const float*)d_in[1];
  const float* Wmlp    = (const float*)d_in[2];
  const float* Wout    = (const float*)d_in[3];
  const float* conv_w  = (const float*)d_in[4];
  const float* conv_b  = (const float*)d_in[5];
  const float* conv_st = (const float*)d_in[6];
  const float* Wx      = (const float*)d_in[7];
  const float* Wdt     = (const float*)d_in[8];
  const float* dt_bias = (const float*)d_in[9];
  const float* A_log   = (const float*)d_in[10];
  const float* Dvec    = (const float*)d_in[11];
  const float* h       = (const float*)d_in[12];
  float* out = (float*)d_out;

  float* ws = (float*)d_ws;
  float* xT  = ws;                       // 81,920
  float* P1  = xT  + 81920;              // 2,621,440  (8 splits x 32 x 10240)
  float* xt  = P1  + 2621440;            // 163,840
  float* res = xt  + 163840;             // 163,840
  float* dbc = res + 163840;             // 6,144
  float* zT  = dbc + 6144;               // 163,840
  float* P4  = zT  + 163840;             // 1,310,720  (16 splits x 32 x 2560)

  hipLaunchKernelGGL(k0_prep,     dim3(320),  dim3(256), 0, stream, x, xT, dbc);
  hipLaunchKernelGGL(gemm_sk,     dim3(1280), dim3(256), 0, stream,
                     Wssm, Wmlp, EE, EE, xT, P1, 10240, 160);
  hipLaunchKernelGGL(k1b_epilogue,dim3(640),  dim3(256), 0, stream, P1, conv_st, conv_w, conv_b, xt, res);
  hipLaunchKernelGGL(k2_dbc,      dim3(192),  dim3(256), 0, stream, xt, Wx, dbc);
  hipLaunchKernelGGL(k3_ssm,      dim3(320),  dim3(256), 0, stream, dbc, Wdt, dt_bias, A_log, Dvec, h, xt, res, zT);
  hipLaunchKernelGGL(gemm_sk,     dim3(640),  dim3(256), 0, stream,
                     Wout, Wout, 1 << 30, DD, zT, P4, DD, 40);
  hipLaunchKernelGGL(k4b_reduce,  dim3(320),  dim3(256), 0, stream, P4, out);
}

// Round 5
// 249.495 us; speedup vs baseline: 1.5167x; 1.0888x over previous
//
#include <hip/hip_runtime.h>
#include <math.h>

#define EE 5120
#define DD 2560
#define BB 32

typedef __attribute__((ext_vector_type(8)))  short  short8;
typedef __attribute__((ext_vector_type(8)))  __bf16 bf16x8;
typedef __attribute__((ext_vector_type(16))) float  f32x16;

// Split fp32 into bf16 hi (truncate) + bf16 lo (truncate of exact residual).
// A = Ah + Al + eps, |eps| <= 2^-16 |A|.
__device__ __forceinline__ void split8(const float* v, short8& hi, short8& lo) {
#pragma unroll
  for (int j = 0; j < 8; ++j) {
    unsigned u = __float_as_uint(v[j]);
    hi[j] = (short)(u >> 16);
    float r = v[j] - __uint_as_float(u & 0xFFFF0000u);
    lo[j] = (short)(__float_as_uint(r) >> 16);
  }
}
#define BC(x) __builtin_bit_cast(bf16x8, x)

// Async global->LDS DMA, 16B per lane (used by k3).
__device__ __forceinline__ void g2l16(const float* g, float* l) {
  __builtin_amdgcn_global_load_lds(
      (const __attribute__((address_space(1))) void*)g,
      (__attribute__((address_space(3))) void*)l, 16, 0, 0);
}

// ---------------------------------------------------------------------------
// K0: transpose x (B,D) -> xT (D,B); zero dbc accumulator.
__global__ __launch_bounds__(256) void k0_prep(const float* __restrict__ x,
                                               float* __restrict__ xT,
                                               float* __restrict__ dbc) {
  int g = blockIdx.x * 256 + threadIdx.x;
  if (g < BB * DD) {
    int b = g / DD, k = g % DD;
    xT[k * BB + b] = x[g];
  }
  if (g < BB * 192) dbc[g] = 0.f;
}

// ---------------------------------------------------------------------------
// MFMA skinny GEMM: P[(so*32+row)*pstride+col] = sum_k xsrc[k][b] * W[k][col]
// via v_mfma_f32_32x32x16_bf16 with 3-way fp32 split (AhBh + AlBh + AhBl).
// Block = 4 waves; block covers 64 cols (2 tiles of 32); wave wv owns k-slice
// [so*320+wv*80, +80) = 5 k16-steps. A (x) preloaded to regs from xsrc (K,32).
// B (weights) loaded straight from global: 8 row-strided dwords per step,
// each 256 B coalesced. Cross-wave reduce of fp32 D-frags in padded LDS.
// A-frag: A[m=lane&31][k=(lane>>5)*8+j]; B-frag: B[k=(lane>>5)*8+j][n=lane&31];
// D: col=lane&31, row=(reg&3)+8*(reg>>2)+4*(lane>>5)  [m74/m101 verified].
__global__ __launch_bounds__(256) void gemm_mfma(const float* __restrict__ W0,
                                                 const float* __restrict__ W1,
                                                 int wsplit, int wstride,
                                                 const float* __restrict__ xsrc,
                                                 float* __restrict__ P,
                                                 int pstride, int ncb) {
  __shared__ float red[4 * 64 * 17];
  const int cb   = blockIdx.x % ncb;
  const int so   = blockIdx.x / ncb;
  const int lane = threadIdx.x & 63;
  const int wv   = __builtin_amdgcn_readfirstlane((int)(threadIdx.x >> 6));
  const int c0   = cb * 64;
  const float* __restrict__ W = (c0 < wsplit) ? W0 : W1;
  const int wc0  = (c0 < wsplit) ? c0 : c0 - wsplit;
  const int kw   = so * 320 + wv * 80;
  const int kl   = (lane >> 5) * 8;          // 0 or 8
  const int ln   = lane & 31;

  // preload A: 5 steps x 8 elems (coalesced 128B rows of xsrc), then split
  float av[5][8];
#pragma unroll
  for (int s = 0; s < 5; ++s)
#pragma unroll
    for (int j = 0; j < 8; ++j)
      av[s][j] = xsrc[(size_t)(kw + s * 16 + kl + j) * BB + ln];
  short8 ah[5], al[5];
#pragma unroll
  for (int s = 0; s < 5; ++s) split8(av[s], ah[s], al[s]);

#pragma unroll
  for (int t = 0; t < 2; ++t) {
    f32x16 acc;
#pragma unroll
    for (int i = 0; i < 16; ++i) acc[i] = 0.f;

    const float* __restrict__ wp =
        W + (size_t)kw * wstride + wc0 + t * 32 + ln;

    float bv0[8], bv1[8];
#pragma unroll
    for (int j = 0; j < 8; ++j) bv0[j] = wp[(size_t)(kl + j) * wstride];
#pragma unroll
    for (int s = 0; s < 5; ++s) {
      float (&cur)[8] = (s & 1) ? bv1 : bv0;
      float (&nxt)[8] = (s & 1) ? bv0 : bv1;
      if (s < 4) {
#pragma unroll
        for (int j = 0; j < 8; ++j)
          nxt[j] = wp[(size_t)((s + 1) * 16 + kl + j) * wstride];
      }
      short8 bh, bl;
      split8(cur, bh, bl);
      acc = __builtin_amdgcn_mfma_f32_32x32x16_bf16(BC(ah[s]), BC(bh), acc, 0, 0, 0);
      acc = __builtin_amdgcn_mfma_f32_32x32x16_bf16(BC(al[s]), BC(bh), acc, 0, 0, 0);
      acc = __builtin_amdgcn_mfma_f32_32x32x16_bf16(BC(ah[s]), BC(bl), acc, 0, 0, 0);
    }

    // cross-wave reduce (4 partials per tile), stride-17 conflict-free
    __syncthreads();
#pragma unroll
    for (int r = 0; r < 16; ++r) red[(wv * 64 + lane) * 17 + r] = acc[r];
    __syncthreads();
#pragma unroll
    for (int q = 0; q < 4; ++q) {
      int r = wv * 4 + q;
      float sum = red[(0 * 64 + lane) * 17 + r] + red[(1 * 64 + lane) * 17 + r] +
                  red[(2 * 64 + lane) * 17 + r] + red[(3 * 64 + lane) * 17 + r];
      int row = (r & 3) + 8 * (r >> 2) + 4 * (lane >> 5);
      P[((size_t)(so * 32 + row)) * pstride + c0 + t * 32 + ln] = sum;
    }
  }
}

// ---------------------------------------------------------------------------
// K1b: reduce the 8 outer partials, fuse conv(4-tap)+silu -> xt, silu -> res.
__global__ __launch_bounds__(256) void k1b_epilogue(const float* __restrict__ P1,
                                                    const float* __restrict__ cs,
                                                    const float* __restrict__ cw,
                                                    const float* __restrict__ cbv,
                                                    float* __restrict__ xt,
                                                    float* __restrict__ res) {
  int g = blockIdx.x * 256 + threadIdx.x;     // 0..163839
  int e = g % EE;
  int b = g / EE;
  float xs = 0.f, xm = 0.f;
#pragma unroll
  for (int so = 0; so < 8; ++so) {
    xs += P1[((size_t)(so * BB + b)) * 10240 + e];
    xm += P1[((size_t)(so * BB + b)) * 10240 + EE + e];
  }
  size_t be = (size_t)b * EE + e;
  const size_t T = (size_t)BB * EE;
  float conv = cs[be] * cw[be] + cs[T + be] * cw[T + be] +
               cs[2 * T + be] * cw[2 * T + be] + xs * cw[3 * T + be] + cbv[be];
  float sig = 1.f / (1.f + expf(-conv));
  xt[be] = conv * sig;
  float sm = 1.f / (1.f + expf(-xm));
  res[be] = xm * sm;
}

// ---------------------------------------------------------------------------
// K2: dbc = xt @ Wx  (32 x 5120 x 192). 192 blocks = 3 cb x 64 k-splits.
__global__ __launch_bounds__(256) void k2_dbc(const float* __restrict__ xt,
                                              const float* __restrict__ Wx,
                                              float* __restrict__ dbc) {
  const int bid  = blockIdx.x;
  const int cbi  = bid % 3;
  const int so   = bid / 3;                   // 0..63
  const int lane = threadIdx.x & 63;
  const int j    = cbi * 64 + lane;           // 0..191
  const int k0   = so * 80 + (int)(threadIdx.x >> 6) * 20;

  float acc[BB];
#pragma unroll
  for (int b = 0; b < BB; ++b) acc[b] = 0.f;

  for (int kk = 0; kk < 20; kk += 4) {
    int k = k0 + kk;
    float w0 = Wx[(size_t)(k + 0) * 192 + j];
    float w1 = Wx[(size_t)(k + 1) * 192 + j];
    float w2 = Wx[(size_t)(k + 2) * 192 + j];
    float w3 = Wx[(size_t)(k + 3) * 192 + j];
#pragma unroll
    for (int b = 0; b < BB; ++b) acc[b] = fmaf(xt[(size_t)b * EE + k + 0], w0, acc[b]);
#pragma unroll
    for (int b = 0; b < BB; ++b) acc[b] = fmaf(xt[(size_t)b * EE + k + 1], w1, acc[b]);
#pragma unroll
    for (int b = 0; b < BB; ++b) acc[b] = fmaf(xt[(size_t)b * EE + k + 2], w2, acc[b]);
#pragma unroll
    for (int b = 0; b < BB; ++b) acc[b] = fmaf(xt[(size_t)b * EE + k + 3], w3, acc[b]);
  }

  __shared__ float red2[4][64][17];
  const int ksid = threadIdx.x >> 6;
#pragma unroll
  for (int half = 0; half < 2; ++half) {
    __syncthreads();
#pragma unroll
    for (int i = 0; i < 16; ++i) red2[ksid][lane][i] = acc[half * 16 + i];
    __syncthreads();
#pragma unroll
    for (int jj = 0; jj < 4; ++jj) {
      int bi = ksid * 4 + jj;
      float v = red2[0][lane][bi] + red2[1][lane][bi] +
                red2[2][lane][bi] + red2[3][lane][bi];
      int b = half * 16 + bi;
      atomicAdd(&dbc[b * 192 + j], v);
    }
  }
}

// ---------------------------------------------------------------------------
// K3: dt-GEMM (K=160, Wdt tile async-staged to LDS) + softplus + SSM step
// + D*xt + residual mul -> zT (E,B). 320 blocks = 80 eb x 4 bg.
__global__ __launch_bounds__(256) void k3_ssm(const float* __restrict__ dbc,
                                              const float* __restrict__ Wdt,
                                              const float* __restrict__ dt_bias,
                                              const float* __restrict__ A_log,
                                              const float* __restrict__ Dvec,
                                              const float* __restrict__ h,
                                              const float* __restrict__ xt,
                                              const float* __restrict__ res,
                                              float* __restrict__ zT) {
  __shared__ float sw[10240];                 // 160 x 64 Wdt tile
  const int eb   = blockIdx.x % 80;
  const int bg   = blockIdx.x / 80;           // 0..3
  const int lane = threadIdx.x & 63;
  const int wv   = __builtin_amdgcn_readfirstlane((int)(threadIdx.x >> 6));
  const int e    = eb * 64 + lane;
  const int bq   = bg * 4 + wv;               // 0..15
  const int b0   = bq * 2, b1 = b0 + 1;

  {
    const int rg = lane >> 4, cg = (lane & 15) * 4;
#pragma unroll
    for (int j = 0; j < 10; ++j) {
      int r = wv * 40 + j * 4 + rg;
      g2l16(Wdt + (size_t)r * EE + eb * 64 + cg, sw + (wv * 40 + j * 4) * 64);
    }
  }
  __syncthreads();                            // barrier drains vmcnt -> DMA landed

  float a0 = 0.f, a1 = 0.f;
  const float* __restrict__ d0 = dbc + b0 * 192;
  const float* __restrict__ d1 = dbc + b1 * 192;
#pragma unroll 4
  for (int r = 0; r < 160; ++r) {
    float w = sw[r * 64 + lane];
    a0 = fmaf(d0[r], w, a0);
    a1 = fmaf(d1[r], w, a1);
  }

  float An[16];
#pragma unroll
  for (int n = 0; n < 16; ++n) An[n] = -expf(A_log[e * 16 + n]);
  const float bias = dt_bias[e];
  const float Dv = Dvec[e];

#pragma unroll
  for (int t = 0; t < 2; ++t) {
    int b = t ? b1 : b0;
    float a = t ? a1 : a0;
    float v = a + bias;
    float dt = (v > 20.f) ? v : log1pf(expf(v));
    size_t be = (size_t)b * EE + e;
    float xb = xt[be];
    const float* __restrict__ hb = h + be * 16;
    const float* __restrict__ Bm = dbc + b * 192 + 160;
    const float* __restrict__ Cm = dbc + b * 192 + 176;
    float y = 0.f;
#pragma unroll
    for (int n = 0; n < 16; ++n) {
      float dA = expf(dt * An[n]);
      float hn = fmaf(hb[n], dA, dt * Bm[n] * xb);
      y = fmaf(hn, Cm[n], y);
    }
    y = fmaf(Dv, xb, y);
    zT[e * BB + b] = y * res[be];
  }
}

// K4b: reduce 16 partials -> final output (B, D) flat.
__global__ __launch_bounds__(256) void k4b_reduce(const float* __restrict__ P4,
                                                  float* __restrict__ out) {
  int g = blockIdx.x * 256 + threadIdx.x;     // 0..81919 == b*DD + d
  int d = g % DD;
  int b = g / DD;
  float s = 0.f;
#pragma unroll
  for (int so = 0; so < 16; ++so) s += P4[((size_t)(so * BB + b)) * DD + d];
  out[g] = s;
}

// ---------------------------------------------------------------------------
extern "C" void kernel_launch(void* const* d_in, const int* in_sizes, int n_in,
                              void* d_out, int out_size, void* d_ws, size_t ws_size,
                              hipStream_t stream) {
  const float* x       = (const float*)d_in[0];
  const float* Wssm    = (const float*)d_in[1];
  const float* Wmlp    = (const float*)d_in[2];
  const float* Wout    = (const float*)d_in[3];
  const float* conv_w  = (const float*)d_in[4];
  const float* conv_b  = (const float*)d_in[5];
  const float* conv_st = (const float*)d_in[6];
  const float* Wx      = (const float*)d_in[7];
  const float* Wdt     = (const float*)d_in[8];
  const float* dt_bias = (const float*)d_in[9];
  const float* A_log   = (const float*)d_in[10];
  const float* Dvec    = (const float*)d_in[11];
  const float* h       = (const float*)d_in[12];
  float* out = (float*)d_out;

  float* ws = (float*)d_ws;
  float* xT  = ws;                       // 81,920
  float* P1  = xT  + 81920;              // 2,621,440  (8 splits x 32 x 10240)
  float* xt  = P1  + 2621440;            // 163,840
  float* res = xt  + 163840;             // 163,840
  float* dbc = res + 163840;             // 6,144
  float* zT  = dbc + 6144;               // 163,840
  float* P4  = zT  + 163840;             // 1,310,720  (16 splits x 32 x 2560)

  hipLaunchKernelGGL(k0_prep,     dim3(320),  dim3(256), 0, stream, x, xT, dbc);
  hipLaunchKernelGGL(gemm_mfma,   dim3(1280), dim3(256), 0, stream,
                     Wssm, Wmlp, EE, EE, xT, P1, 10240, 160);
  hipLaunchKernelGGL(k1b_epilogue,dim3(640),  dim3(256), 0, stream, P1, conv_st, conv_w, conv_b, xt, res);
  hipLaunchKernelGGL(k2_dbc,      dim3(192),  dim3(256), 0, stream, xt, Wx, dbc);
  hipLaunchKernelGGL(k3_ssm,      dim3(320),  dim3(256), 0, stream, dbc, Wdt, dt_bias, A_log, Dvec, h, xt, res, zT);
  hipLaunchKernelGGL(gemm_mfma,   dim3(640),  dim3(256), 0, stream,
                     Wout, Wout, 1 << 30, DD, zT, P4, DD, 40);
  hipLaunchKernelGGL(k4b_reduce,  dim3(320),  dim3(256), 0, stream, P4, out);
}